// Round 11
// baseline (100.423 us; speedup 1.0000x reference)
//
#include <hip/hip_runtime.h>
#include <math.h>

// WeightedHausdorffDistance on MI355X — SINGLE-dispatch version.
// B=8, H=W=256 (N=65536 pixels), M=128 points.
// 1024 blocks (128/batch, 4 waves/SIMD). Each block:
//   - computes its 512 pixels vs all 128 points (fused term1 row-min +
//     term2 column-min via transposed butterfly -> global uint atomicMin)
//   - writes term1/focal partials
//   - last finishing block (atomicAdd done-counter) reduces everything -> out.
// ws poison exploitation (documented 0xAA):
//   - colmin needs NO init: all stored values have uint bits < 0x7F800000
//     < 0xAAAAAAAA, so atomicMin vs poison is correct.
//   - done-counter starts at 0xAAAAAAAA; last block sees old == POISON+NBLK-1.

#define HH 256
#define WW 256
#define NPIX (HH*WW)
#define MM 128
#define BB 8
#define MAXDIST 362.03867196751236f   // sqrt(256^2+256^2)
#define PBLK 128                       // blocks per batch
#define NBLK (BB*PBLK)                 // 1024 blocks = 4 waves/SIMD
#define TPB 256                        // threads per block
#define PXT 2                          // pixels per thread (contiguous, same row)
#define MCH 16                         // m-chunk (register-resident)
#define NCH (MM/MCH)
#define POISON 0xAAAAAAAAu
#define LASTTOK (POISON + (unsigned)(NBLK - 1))

#if defined(__has_builtin)
#if __has_builtin(__builtin_amdgcn_sqrtf)
#define FSQRT(x) __builtin_amdgcn_sqrtf(x)
#else
#define FSQRT(x) sqrtf(x)
#endif
#else
#define FSQRT(x) sqrtf(x)
#endif

__device__ __forceinline__ float wave_sum(float v) {
#pragma unroll
  for (int off = 32; off > 0; off >>= 1) v += __shfl_xor(v, off, 64);
  return v;
}

__global__ __launch_bounds__(TPB, 4) void whd_fused(
    const float* __restrict__ prob, const float* __restrict__ gtmap,
    const float* __restrict__ gt, const float* __restrict__ osz,
    unsigned* __restrict__ colmin,      // [BB*MM] uints, poison-initialized
    float* __restrict__ partials,       // [NBLK*4]
    unsigned* __restrict__ counter,     // 1 uint, poison-initialized
    float* __restrict__ out) {
  const int b   = blockIdx.x >> 7;          // / PBLK
  const int blk = blockIdx.x & (PBLK - 1);
  const int tid = threadIdx.x;
  const int lane = tid & 63;

  __shared__ float2 sgt[MM];
  __shared__ float wred[TPB / 64][4];
  __shared__ int lastFlag;
  __shared__ float sT[TPB / 64];
  __shared__ float sA[BB], sC[BB], sF[BB], sG[BB];

  const float ny = osz[b * 2 + 0] * (1.0f / HH);
  const float nx = osz[b * 2 + 1] * (1.0f / WW);

  if (tid < MM) {
    float gy = gt[(b * MM + tid) * 2 + 0] * ny;
    float gx = gt[(b * MM + tid) * 2 + 1] * nx;
    sgt[tid] = make_float2(gy, gx);
  }
  __syncthreads();

  const int pixBase = blk * (NPIX / PBLK) + tid * PXT;  // 512 pixels/block, 2 rows
  const float pyf = (float)(pixBase >> 8) * ny;         // row * norm_y
  const int col0 = pixBase & (WW - 1);

  const float* pp = prob + b * NPIX + pixBase;
  float2 pv = *(const float2*)(pp);
  float p[PXT] = {pv.x, pv.y};

  float pxf[PXT], bb[PXT], md[PXT];
#pragma unroll
  for (int i = 0; i < PXT; i++) {
    pxf[i] = (float)(col0 + i) * nx;
    bb[i]  = (1.0f - p[i]) * MAXDIST;   // (1-p)*MAX_DIST, hoisted
    md[i]  = 3.0e38f;                   // running min_m d
  }

#pragma unroll 1
  for (int c = 0; c < NCH; c++) {
    float gx[MCH], dy2[MCH], cm[MCH];
#pragma unroll
    for (int j = 0; j < MCH; j++) {
      float2 g = sgt[c * MCH + j];      // wave-uniform LDS read -> broadcast
      float dy = pyf - g.x;
      dy2[j] = dy * dy;                 // row shared by both pixels of this thread
      gx[j]  = g.y;
      cm[j]  = 3.0e38f;
    }
#pragma unroll
    for (int i = 0; i < PXT; i++) {
      const float pi = p[i], bi = bb[i], xi = pxf[i];
      float mdi = md[i];
#pragma unroll
      for (int j = 0; j < MCH; j++) {
        float dx = xi - gx[j];
        float d  = FSQRT(fmaf(dx, dx, dy2[j]));
        mdi   = fminf(mdi, d);                       // term1 row-min
        cm[j] = fminf(cm[j], fmaf(pi, d, bi));       // term2 column-min
      }
      md[i] = mdi;
    }

    // Transposed butterfly: reduce 16 column-mins over 64 lanes in-place.
    // After stages xor-32/16/8/4 + finish xor-1/2, lane l holds full wave min
    // for m = l>>2. min is exact & commutative -> deterministic.
    {
      const bool hi5 = (lane & 32) != 0;
#pragma unroll
      for (int k = 0; k < 8; k++) {
        float keep = hi5 ? cm[k + 8] : cm[k];
        float send = hi5 ? cm[k] : cm[k + 8];
        cm[k] = fminf(keep, __shfl_xor(send, 32, 64));
      }
      const bool hi4 = (lane & 16) != 0;
#pragma unroll
      for (int k = 0; k < 4; k++) {
        float keep = hi4 ? cm[k + 4] : cm[k];
        float send = hi4 ? cm[k] : cm[k + 4];
        cm[k] = fminf(keep, __shfl_xor(send, 16, 64));
      }
      const bool hi3 = (lane & 8) != 0;
#pragma unroll
      for (int k = 0; k < 2; k++) {
        float keep = hi3 ? cm[k + 2] : cm[k];
        float send = hi3 ? cm[k] : cm[k + 2];
        cm[k] = fminf(keep, __shfl_xor(send, 8, 64));
      }
      const bool hi2 = (lane & 4) != 0;
      {
        float keep = hi2 ? cm[1] : cm[0];
        float send = hi2 ? cm[0] : cm[1];
        cm[0] = fminf(keep, __shfl_xor(send, 4, 64));
      }
      float v = cm[0];
      v = fminf(v, __shfl_xor(v, 1, 64));
      v = fminf(v, __shfl_xor(v, 2, 64));
      // 16 writer lanes -> global uint atomicMin, distinct consecutive addrs.
      // No init needed: value bits < 0x7F800000 < poison 0xAAAAAAAA.
      if ((lane & 3) == 0)
        atomicMin(&colmin[b * MM + c * MCH + (lane >> 2)], __float_as_uint(v));
    }
  }

  // term1 partial sums
  float spd = 0.0f, sp = 0.0f;
#pragma unroll
  for (int i = 0; i < PXT; i++) {
    spd = fmaf(p[i], md[i], spd);
    sp += p[i];
  }

  // focal loss: only last batch's blocks touch gt_map
  float fs = 0.0f, fc = 0.0f;
  if (b == BB - 1) {
    const float* gp = gtmap + b * NPIX + pixBase;
    float2 gv2 = *(const float2*)(gp);
    float gv[PXT] = {gv2.x, gv2.y};
#pragma unroll
    for (int i = 0; i < PXT; i++) {
      float g = gv[i], pi = p[i];
      if (g == 1.0f) {
        float om = 1.0f - pi;
        fs += om * om * logf(pi);
        fc += 1.0f;
      } else {
        float t = 1.0f - g, t2 = t * t;
        fs += t2 * t2 * pi * pi * log1pf(-pi);
      }
    }
  }

  spd = wave_sum(spd);
  sp  = wave_sum(sp);
  fs  = wave_sum(fs);
  fc  = wave_sum(fc);

  const int wid = tid >> 6;
  if (lane == 0) {
    wred[wid][0] = spd; wred[wid][1] = sp; wred[wid][2] = fs; wred[wid][3] = fc;
  }
  __syncthreads();   // all LDS writes + this block's atomicMins complete

  if (tid == 0) {
    float a = 0, c2 = 0, e = 0, f = 0;
#pragma unroll
    for (int w = 0; w < TPB / 64; w++) {
      a += wred[w][0]; c2 += wred[w][1]; e += wred[w][2]; f += wred[w][3];
    }
    float* pt = partials + blockIdx.x * 4;
    pt[0] = a; pt[1] = c2; pt[2] = e; pt[3] = f;
    __threadfence();                        // release partials + atomics
    unsigned old = atomicAdd(counter, 1u);  // counter starts at POISON
    lastFlag = (old == LASTTOK) ? 1 : 0;
  }
  __syncthreads();
  if (lastFlag == 0) return;

  // ---- last block: final reduce (reads via atomic-RMW for cross-XCD safety)
  __threadfence();                          // acquire

  // term2: sum of all B*M column mins (fixed order -> deterministic)
  float s = 0.0f;
  for (int i = tid; i < BB * MM; i += TPB)
    s += __uint_as_float(atomicAdd(&colmin[i], 0u));
  s = wave_sum(s);
  if (lane == 0) sT[wid] = s;

  // term1/focal: 32 threads per batch over that batch's 128 block partials
  const int g = tid >> 5;       // batch 0..7
  const int i = tid & 31;
  float a = 0, c = 0, e = 0, f = 0;
  for (int k = i; k < PBLK; k += 32) {
    float* pt = partials + (g * PBLK + k) * 4;
    a += atomicAdd(pt + 0, 0.0f);
    c += atomicAdd(pt + 1, 0.0f);
    e += atomicAdd(pt + 2, 0.0f);
    f += atomicAdd(pt + 3, 0.0f);
  }
#pragma unroll
  for (int off = 16; off > 0; off >>= 1) {   // stays within 32-lane batch group
    a += __shfl_xor(a, off, 64); c += __shfl_xor(c, off, 64);
    e += __shfl_xor(e, off, 64); f += __shfl_xor(f, off, 64);
  }
  if (i == 0) { sA[g] = a; sC[g] = c; sF[g] = e; sG[g] = f; }
  __syncthreads();

  if (tid == 0) {
    float t2 = (sT[0] + sT[1] + sT[2] + sT[3]) * (1.0f / (BB * MM));
    float t1 = 0.0f;
    for (int b2 = 0; b2 < BB; b2++) t1 += sA[b2] / (sC[b2] + 1e-6f);
    t1 *= (1.0f / BB);
    float fsum = 0.0f, fcnt = 0.0f;
    for (int b2 = 0; b2 < BB; b2++) { fsum += sF[b2]; fcnt += sG[b2]; }
    out[0] = t1 + t2 - fsum / fcnt;   // -(focal_sum / pos_count)
  }
}

extern "C" void kernel_launch(void* const* d_in, const int* in_sizes, int n_in,
                              void* d_out, int out_size, void* d_ws, size_t ws_size,
                              hipStream_t stream) {
  const float* prob  = (const float*)d_in[0];  // [B,H,W]
  const float* gtmap = (const float*)d_in[1];  // [B,H,W]
  const float* gt    = (const float*)d_in[2];  // [B,M,2]
  const float* osz   = (const float*)d_in[3];  // [B,2]
  float* out = (float*)d_out;

  unsigned* colmin  = (unsigned*)d_ws;                            // 1024 uints (4 KB)
  float* partials   = (float*)((char*)d_ws + 4096);               // NBLK*4 floats (16 KB)
  unsigned* counter = (unsigned*)((char*)d_ws + 4096 + NBLK * 16); // 1 uint

  whd_fused<<<NBLK, TPB, 0, stream>>>(prob, gtmap, gt, osz, colmin, partials,
                                      counter, out);
}

// Round 12
// 98.927 us; speedup vs baseline: 1.0151x; 1.0151x over previous
//
#include <hip/hip_runtime.h>
#include <math.h>

// WeightedHausdorffDistance on MI355X — single-dispatch, raw v_sqrt_f32.
// B=8, H=W=256 (N=65536 pixels), M=128 points.
// 1024 blocks (128/batch). Per block: 512 pixels vs 128 points fused
// (term1 row-min in registers, term2 column-min via transposed butterfly ->
// global uint atomicMin vs 0xAA poison), partials + poison-counter tail reduce.
// R11 HW-verified: passed, absmax 0.0, kernel 46us, VALUBusy 30%.
// R12 change (ONE variable): FSQRT = inline-asm v_sqrt_f32 (sqrtf() lowers to
// ~12-instr IEEE expansion; 67M pairs made that the dominant cost).

#define HH 256
#define WW 256
#define NPIX (HH*WW)
#define MM 128
#define BB 8
#define MAXDIST 362.03867196751236f   // sqrt(256^2+256^2)
#define PBLK 128                       // blocks per batch
#define NBLK (BB*PBLK)                 // 1024 blocks
#define TPB 256                        // threads per block
#define PXT 2                          // pixels per thread (contiguous, same row)
#define MCH 16                         // m-chunk (register-resident)
#define NCH (MM/MCH)
#define POISON 0xAAAAAAAAu
#define LASTTOK (POISON + (unsigned)(NBLK - 1))

__device__ __forceinline__ float fast_sqrt(float x) {
  float r;
  asm volatile("v_sqrt_f32 %0, %1" : "=v"(r) : "v"(x));  // single VOP1, ~1ulp
  return r;
}

__device__ __forceinline__ float wave_sum(float v) {
#pragma unroll
  for (int off = 32; off > 0; off >>= 1) v += __shfl_xor(v, off, 64);
  return v;
}

__global__ __launch_bounds__(TPB, 4) void whd_fused(
    const float* __restrict__ prob, const float* __restrict__ gtmap,
    const float* __restrict__ gt, const float* __restrict__ osz,
    unsigned* __restrict__ colmin,      // [BB*MM] uints, poison-initialized
    float* __restrict__ partials,       // [NBLK*4]
    unsigned* __restrict__ counter,     // 1 uint, poison-initialized
    float* __restrict__ out) {
  const int b   = blockIdx.x >> 7;          // / PBLK
  const int blk = blockIdx.x & (PBLK - 1);
  const int tid = threadIdx.x;
  const int lane = tid & 63;

  __shared__ float2 sgt[MM];
  __shared__ float wred[TPB / 64][4];
  __shared__ int lastFlag;
  __shared__ float sT[TPB / 64];
  __shared__ float sA[BB], sC[BB], sF[BB], sG[BB];

  const float ny = osz[b * 2 + 0] * (1.0f / HH);
  const float nx = osz[b * 2 + 1] * (1.0f / WW);

  if (tid < MM) {
    float gy = gt[(b * MM + tid) * 2 + 0] * ny;
    float gx = gt[(b * MM + tid) * 2 + 1] * nx;
    sgt[tid] = make_float2(gy, gx);
  }
  __syncthreads();

  const int pixBase = blk * (NPIX / PBLK) + tid * PXT;  // 512 pixels/block, 2 rows
  const float pyf = (float)(pixBase >> 8) * ny;         // row * norm_y
  const int col0 = pixBase & (WW - 1);

  const float* pp = prob + b * NPIX + pixBase;
  float2 pv = *(const float2*)(pp);
  float p[PXT] = {pv.x, pv.y};

  float pxf[PXT], bb[PXT], md[PXT];
#pragma unroll
  for (int i = 0; i < PXT; i++) {
    pxf[i] = (float)(col0 + i) * nx;
    bb[i]  = (1.0f - p[i]) * MAXDIST;   // (1-p)*MAX_DIST, hoisted
    md[i]  = 3.0e38f;                   // running min_m d
  }

#pragma unroll 1
  for (int c = 0; c < NCH; c++) {
    float gx[MCH], dy2[MCH], cm[MCH];
#pragma unroll
    for (int j = 0; j < MCH; j++) {
      float2 g = sgt[c * MCH + j];      // wave-uniform LDS read -> broadcast
      float dy = pyf - g.x;
      dy2[j] = dy * dy;                 // row shared by both pixels of this thread
      gx[j]  = g.y;
      cm[j]  = 3.0e38f;
    }
#pragma unroll
    for (int i = 0; i < PXT; i++) {
      const float pi = p[i], bi = bb[i], xi = pxf[i];
      float mdi = md[i];
#pragma unroll
      for (int j = 0; j < MCH; j++) {
        float dx = xi - gx[j];
        float d  = fast_sqrt(fmaf(dx, dx, dy2[j]));
        mdi   = fminf(mdi, d);                       // term1 row-min
        cm[j] = fminf(cm[j], fmaf(pi, d, bi));       // term2 column-min
      }
      md[i] = mdi;
    }

    // Transposed butterfly: reduce 16 column-mins over 64 lanes in-place.
    // After stages xor-32/16/8/4 + finish xor-1/2, lane l holds full wave min
    // for m = l>>2. min is exact & commutative -> deterministic.
    {
      const bool hi5 = (lane & 32) != 0;
#pragma unroll
      for (int k = 0; k < 8; k++) {
        float keep = hi5 ? cm[k + 8] : cm[k];
        float send = hi5 ? cm[k] : cm[k + 8];
        cm[k] = fminf(keep, __shfl_xor(send, 32, 64));
      }
      const bool hi4 = (lane & 16) != 0;
#pragma unroll
      for (int k = 0; k < 4; k++) {
        float keep = hi4 ? cm[k + 4] : cm[k];
        float send = hi4 ? cm[k] : cm[k + 4];
        cm[k] = fminf(keep, __shfl_xor(send, 16, 64));
      }
      const bool hi3 = (lane & 8) != 0;
#pragma unroll
      for (int k = 0; k < 2; k++) {
        float keep = hi3 ? cm[k + 2] : cm[k];
        float send = hi3 ? cm[k] : cm[k + 2];
        cm[k] = fminf(keep, __shfl_xor(send, 8, 64));
      }
      const bool hi2 = (lane & 4) != 0;
      {
        float keep = hi2 ? cm[1] : cm[0];
        float send = hi2 ? cm[0] : cm[1];
        cm[0] = fminf(keep, __shfl_xor(send, 4, 64));
      }
      float v = cm[0];
      v = fminf(v, __shfl_xor(v, 1, 64));
      v = fminf(v, __shfl_xor(v, 2, 64));
      // 16 writer lanes -> global uint atomicMin, distinct consecutive addrs.
      // No init needed: value bits < 0x7F800000 < poison 0xAAAAAAAA.
      if ((lane & 3) == 0)
        atomicMin(&colmin[b * MM + c * MCH + (lane >> 2)], __float_as_uint(v));
    }
  }

  // term1 partial sums
  float spd = 0.0f, sp = 0.0f;
#pragma unroll
  for (int i = 0; i < PXT; i++) {
    spd = fmaf(p[i], md[i], spd);
    sp += p[i];
  }

  // focal loss: only last batch's blocks touch gt_map
  float fs = 0.0f, fc = 0.0f;
  if (b == BB - 1) {
    const float* gp = gtmap + b * NPIX + pixBase;
    float2 gv2 = *(const float2*)(gp);
    float gv[PXT] = {gv2.x, gv2.y};
#pragma unroll
    for (int i = 0; i < PXT; i++) {
      float g = gv[i], pi = p[i];
      if (g == 1.0f) {
        float om = 1.0f - pi;
        fs += om * om * logf(pi);
        fc += 1.0f;
      } else {
        float t = 1.0f - g, t2 = t * t;
        fs += t2 * t2 * pi * pi * log1pf(-pi);
      }
    }
  }

  spd = wave_sum(spd);
  sp  = wave_sum(sp);
  fs  = wave_sum(fs);
  fc  = wave_sum(fc);

  const int wid = tid >> 6;
  if (lane == 0) {
    wred[wid][0] = spd; wred[wid][1] = sp; wred[wid][2] = fs; wred[wid][3] = fc;
  }
  __syncthreads();   // all LDS writes + this block's atomicMins complete

  if (tid == 0) {
    float a = 0, c2 = 0, e = 0, f = 0;
#pragma unroll
    for (int w = 0; w < TPB / 64; w++) {
      a += wred[w][0]; c2 += wred[w][1]; e += wred[w][2]; f += wred[w][3];
    }
    float* pt = partials + blockIdx.x * 4;
    pt[0] = a; pt[1] = c2; pt[2] = e; pt[3] = f;
    __threadfence();                        // release partials + atomics
    unsigned old = atomicAdd(counter, 1u);  // counter starts at POISON
    lastFlag = (old == LASTTOK) ? 1 : 0;
  }
  __syncthreads();
  if (lastFlag == 0) return;

  // ---- last block: final reduce (reads via atomic-RMW for cross-XCD safety)
  __threadfence();                          // acquire

  // term2: sum of all B*M column mins (fixed order -> deterministic)
  float s = 0.0f;
  for (int i = tid; i < BB * MM; i += TPB)
    s += __uint_as_float(atomicAdd(&colmin[i], 0u));
  s = wave_sum(s);
  if (lane == 0) sT[wid] = s;

  // term1/focal: 32 threads per batch over that batch's 128 block partials
  const int g = tid >> 5;       // batch 0..7
  const int i = tid & 31;
  float a = 0, c = 0, e = 0, f = 0;
  for (int k = i; k < PBLK; k += 32) {
    float* pt = partials + (g * PBLK + k) * 4;
    a += atomicAdd(pt + 0, 0.0f);
    c += atomicAdd(pt + 1, 0.0f);
    e += atomicAdd(pt + 2, 0.0f);
    f += atomicAdd(pt + 3, 0.0f);
  }
#pragma unroll
  for (int off = 16; off > 0; off >>= 1) {   // stays within 32-lane batch group
    a += __shfl_xor(a, off, 64); c += __shfl_xor(c, off, 64);
    e += __shfl_xor(e, off, 64); f += __shfl_xor(f, off, 64);
  }
  if (i == 0) { sA[g] = a; sC[g] = c; sF[g] = e; sG[g] = f; }
  __syncthreads();

  if (tid == 0) {
    float t2 = (sT[0] + sT[1] + sT[2] + sT[3]) * (1.0f / (BB * MM));
    float t1 = 0.0f;
    for (int b2 = 0; b2 < BB; b2++) t1 += sA[b2] / (sC[b2] + 1e-6f);
    t1 *= (1.0f / BB);
    float fsum = 0.0f, fcnt = 0.0f;
    for (int b2 = 0; b2 < BB; b2++) { fsum += sF[b2]; fcnt += sG[b2]; }
    out[0] = t1 + t2 - fsum / fcnt;   // -(focal_sum / pos_count)
  }
}

extern "C" void kernel_launch(void* const* d_in, const int* in_sizes, int n_in,
                              void* d_out, int out_size, void* d_ws, size_t ws_size,
                              hipStream_t stream) {
  const float* prob  = (const float*)d_in[0];  // [B,H,W]
  const float* gtmap = (const float*)d_in[1];  // [B,H,W]
  const float* gt    = (const float*)d_in[2];  // [B,M,2]
  const float* osz   = (const float*)d_in[3];  // [B,2]
  float* out = (float*)d_out;

  unsigned* colmin  = (unsigned*)d_ws;                            // 1024 uints (4 KB)
  float* partials   = (float*)((char*)d_ws + 4096);               // NBLK*4 floats (16 KB)
  unsigned* counter = (unsigned*)((char*)d_ws + 4096 + NBLK * 16); // 1 uint

  whd_fused<<<NBLK, TPB, 0, stream>>>(prob, gtmap, gt, osz, colmin, partials,
                                      counter, out);
}

// Round 13
// 86.237 us; speedup vs baseline: 1.1645x; 1.1472x over previous
//
#include <hip/hip_runtime.h>
#include <math.h>

// WeightedHausdorffDistance on MI355X — single dispatch, wave-owns-m-range.
// B=8, H=W=256 (N=65536 px), M=128 points. 1024 blocks x 256 thr (4 waves).
// Block owns 512 pixels (2 image rows). Wave w owns m in [32w, 32w+32):
//   lane scans 8 pixel-groups x 32 m with gt/cm in REGISTERS (gt read from
//   LDS once; cm butterflied ONCE at end -> scm -> 128 global atomicMin).
//   Per-pixel min over the wave's m goes to mdw[4][512] (plain LDS stores),
//   combined after one barrier for term1.
// R11/R12 HW data: per-chunk structure stalled 70% (VALUBusy 32%, 46us);
// this removes per-chunk LDS re-reads, 7/8 butterflies, per-chunk atomics.
// Tail (0xAA poison counter + final reduce) byte-identical to verified r11.

#define HH 256
#define WW 256
#define NPIX (HH*WW)
#define MM 128
#define BB 8
#define MAXDIST 362.03867196751236f   // sqrt(256^2+256^2)
#define PBLK 128                       // blocks per batch
#define NBLK (BB*PBLK)                 // 1024 blocks
#define TPB 256                        // threads per block
#define NW 4                           // waves per block
#define MW 32                          // m-points per wave
#define PIXB 512                       // pixels per block (2 rows)
#define POISON 0xAAAAAAAAu
#define LASTTOK (POISON + (unsigned)(NBLK - 1))

__device__ __forceinline__ float fast_sqrt(float x) {
  float r;
  asm("v_sqrt_f32 %0, %1" : "=v"(r) : "v"(x));  // single VOP1 (verified r12)
  return r;
}

__device__ __forceinline__ float wave_sum(float v) {
#pragma unroll
  for (int off = 32; off > 0; off >>= 1) v += __shfl_xor(v, off, 64);
  return v;
}

__global__ __launch_bounds__(TPB, 4) void whd_fused(
    const float* __restrict__ prob, const float* __restrict__ gtmap,
    const float* __restrict__ gt, const float* __restrict__ osz,
    unsigned* __restrict__ colmin,      // [BB*MM] uints, poison-initialized
    float* __restrict__ partials,       // [NBLK*4]
    unsigned* __restrict__ counter,     // 1 uint, poison-initialized
    float* __restrict__ out) {
  const int b    = blockIdx.x >> 7;          // / PBLK
  const int blk  = blockIdx.x & (PBLK - 1);
  const int tid  = threadIdx.x;
  const int lane = tid & 63;
  const int w    = tid >> 6;

  __shared__ float2 sgt[MM];          // gt * norm
  __shared__ float  sp[PIXB];         // p per pixel
  __shared__ float  mdw[NW * PIXB];   // per-wave per-pixel min over its 32 m
  __shared__ float  scm[MM];          // per-block column mins
  __shared__ float  wred[NW][4];
  __shared__ int    lastFlag;
  __shared__ float  sT[NW];
  __shared__ float  sA[BB], sC[BB], sF[BB], sG[BB];

  const float ny = osz[b * 2 + 0] * (1.0f / HH);
  const float nx = osz[b * 2 + 1] * (1.0f / WW);

  if (tid < MM) {
    float gy = gt[(b * MM + tid) * 2 + 0] * ny;
    float gx = gt[(b * MM + tid) * 2 + 1] * nx;
    sgt[tid] = make_float2(gy, gx);
  }

  // load this thread's 2 pixels; stash p; focal at load (same as r11)
  const int pixBase = blk * PIXB + tid * 2;
  const float2 pv = *(const float2*)(prob + b * NPIX + pixBase);
  const float p0 = pv.x, p1 = pv.y;
  sp[tid * 2] = p0;
  sp[tid * 2 + 1] = p1;
  const float spsum = p0 + p1;
  float fs = 0.0f, fc = 0.0f;
  if (b == BB - 1) {
    const float2 gv = *(const float2*)(gtmap + b * NPIX + pixBase);
    {
      float g = gv.x, pi = p0;
      if (g == 1.0f) { float om = 1.0f - pi; fs += om * om * logf(pi); fc += 1.0f; }
      else { float t = 1.0f - g, t2 = t * t; fs += t2 * t2 * pi * pi * log1pf(-pi); }
    }
    {
      float g = gv.y, pi = p1;
      if (g == 1.0f) { float om = 1.0f - pi; fs += om * om * logf(pi); fc += 1.0f; }
      else { float t = 1.0f - g, t2 = t * t; fs += t2 * t2 * pi * pi * log1pf(-pi); }
    }
  }
  __syncthreads();

  // per-wave register setup: 32 gt-x, 32 dy^2 (row 0), 32 running col-mins
  const float pyf0 = (float)(2 * blk) * ny;
  const float pyf1 = (float)(2 * blk + 1) * ny;
  float gxr[MW], dy2[MW], cm[MW];
#pragma unroll
  for (int j = 0; j < MW; j++) {
    float2 g2 = sgt[w * MW + j];      // wave-uniform -> broadcast, ONCE
    gxr[j] = g2.y;
    cm[j]  = 3.0e38f;
    float dy = pyf0 - g2.x;
    dy2[j] = dy * dy;
  }

#pragma unroll 1
  for (int g = 0; g < 8; g++) {
    if (g == 4) {                      // row switch: recompute dy^2 (uniform branch)
#pragma unroll
      for (int j = 0; j < MW; j++) {
        float dy = pyf1 - sgt[w * MW + j].x;
        dy2[j] = dy * dy;
      }
    }
    const float pp = sp[g * 64 + lane];            // 2-way bank alias: free
    const float bi = (1.0f - pp) * MAXDIST;
    const float xi = (float)(((g & 3) << 6) + lane) * nx;
    float md0 = 3.0e38f, md1 = 3.0e38f;            // split min chains
#pragma unroll
    for (int j = 0; j < MW; j += 2) {
      float dx0 = xi - gxr[j];
      float d0  = fast_sqrt(fmaf(dx0, dx0, dy2[j]));
      md0   = fminf(md0, d0);
      cm[j] = fminf(cm[j], fmaf(pp, d0, bi));
      float dx1 = xi - gxr[j + 1];
      float d1  = fast_sqrt(fmaf(dx1, dx1, dy2[j + 1]));
      md1       = fminf(md1, d1);
      cm[j + 1] = fminf(cm[j + 1], fmaf(pp, d1, bi));
    }
    mdw[w * PIXB + g * 64 + lane] = fminf(md0, md1);
  }

  // ONE butterfly: 32 values over 64 lanes (value-halving xor 32/16/8/4/2,
  // finish xor-1). Lane l ends with full wave min for m_local=(l>>1)&31.
  {
    const bool h5 = (lane & 32) != 0;
#pragma unroll
    for (int k = 0; k < 16; k++) {
      float keep = h5 ? cm[k + 16] : cm[k];
      float send = h5 ? cm[k] : cm[k + 16];
      cm[k] = fminf(keep, __shfl_xor(send, 32, 64));
    }
    const bool h4 = (lane & 16) != 0;
#pragma unroll
    for (int k = 0; k < 8; k++) {
      float keep = h4 ? cm[k + 8] : cm[k];
      float send = h4 ? cm[k] : cm[k + 8];
      cm[k] = fminf(keep, __shfl_xor(send, 16, 64));
    }
    const bool h3 = (lane & 8) != 0;
#pragma unroll
    for (int k = 0; k < 4; k++) {
      float keep = h3 ? cm[k + 4] : cm[k];
      float send = h3 ? cm[k] : cm[k + 4];
      cm[k] = fminf(keep, __shfl_xor(send, 8, 64));
    }
    const bool h2 = (lane & 4) != 0;
#pragma unroll
    for (int k = 0; k < 2; k++) {
      float keep = h2 ? cm[k + 2] : cm[k];
      float send = h2 ? cm[k] : cm[k + 2];
      cm[k] = fminf(keep, __shfl_xor(send, 4, 64));
    }
    const bool h1 = (lane & 2) != 0;
    {
      float keep = h1 ? cm[1] : cm[0];
      float send = h1 ? cm[0] : cm[1];
      cm[0] = fminf(keep, __shfl_xor(send, 2, 64));
    }
    float v = fminf(cm[0], __shfl_xor(cm[0], 1, 64));
    if ((lane & 1) == 0) scm[w * MW + ((lane >> 1) & 31)] = v;  // exclusive writers
  }
  __syncthreads();   // mdw + scm complete

  // term1 combine (this thread's own 2 pixels; p0/p1 still in regs)
  const int px0 = 2 * tid, px1 = 2 * tid + 1;
  float mdf0 = fminf(fminf(mdw[0 * PIXB + px0], mdw[1 * PIXB + px0]),
                     fminf(mdw[2 * PIXB + px0], mdw[3 * PIXB + px0]));
  float mdf1 = fminf(fminf(mdw[0 * PIXB + px1], mdw[1 * PIXB + px1]),
                     fminf(mdw[2 * PIXB + px1], mdw[3 * PIXB + px1]));
  float spd = 0.0f;
  spd = fmaf(p0, mdf0, spd);
  spd = fmaf(p1, mdf1, spd);

  // term2: one atomic burst per block (vs poison; bits < 0x7F800000 < 0xAA..)
  if (tid < MM) atomicMin(&colmin[b * MM + tid], __float_as_uint(scm[tid]));

  spd = wave_sum(spd);
  float spw = wave_sum(spsum);
  fs = wave_sum(fs);
  fc = wave_sum(fc);
  if (lane == 0) {
    wred[w][0] = spd; wred[w][1] = spw; wred[w][2] = fs; wred[w][3] = fc;
  }
  __syncthreads();   // drains colmin atomics (vmcnt) + wred visible

  if (tid == 0) {
    float a = 0, c2 = 0, e = 0, f = 0;
#pragma unroll
    for (int wv = 0; wv < NW; wv++) {
      a += wred[wv][0]; c2 += wred[wv][1]; e += wred[wv][2]; f += wred[wv][3];
    }
    float* pt = partials + blockIdx.x * 4;
    pt[0] = a; pt[1] = c2; pt[2] = e; pt[3] = f;
    __threadfence();                        // release partials + atomics
    unsigned old = atomicAdd(counter, 1u);  // counter starts at POISON
    lastFlag = (old == LASTTOK) ? 1 : 0;
  }
  __syncthreads();
  if (lastFlag == 0) return;

  // ---- last block: final reduce (reads via atomic-RMW for cross-XCD safety)
  __threadfence();                          // acquire

  float s = 0.0f;
  for (int i = tid; i < BB * MM; i += TPB)
    s += __uint_as_float(atomicAdd(&colmin[i], 0u));
  s = wave_sum(s);
  if (lane == 0) sT[w] = s;

  const int gb = tid >> 5;      // batch 0..7
  const int i  = tid & 31;
  float a = 0, c = 0, e = 0, f = 0;
  for (int k = i; k < PBLK; k += 32) {
    float* pt = partials + (gb * PBLK + k) * 4;
    a += atomicAdd(pt + 0, 0.0f);
    c += atomicAdd(pt + 1, 0.0f);
    e += atomicAdd(pt + 2, 0.0f);
    f += atomicAdd(pt + 3, 0.0f);
  }
#pragma unroll
  for (int off = 16; off > 0; off >>= 1) {   // stays within 32-lane batch group
    a += __shfl_xor(a, off, 64); c += __shfl_xor(c, off, 64);
    e += __shfl_xor(e, off, 64); f += __shfl_xor(f, off, 64);
  }
  if (i == 0) { sA[gb] = a; sC[gb] = c; sF[gb] = e; sG[gb] = f; }
  __syncthreads();

  if (tid == 0) {
    float t2 = (sT[0] + sT[1] + sT[2] + sT[3]) * (1.0f / (BB * MM));
    float t1 = 0.0f;
    for (int b2 = 0; b2 < BB; b2++) t1 += sA[b2] / (sC[b2] + 1e-6f);
    t1 *= (1.0f / BB);
    float fsum = 0.0f, fcnt = 0.0f;
    for (int b2 = 0; b2 < BB; b2++) { fsum += sF[b2]; fcnt += sG[b2]; }
    out[0] = t1 + t2 - fsum / fcnt;   // -(focal_sum / pos_count)
  }
}

extern "C" void kernel_launch(void* const* d_in, const int* in_sizes, int n_in,
                              void* d_out, int out_size, void* d_ws, size_t ws_size,
                              hipStream_t stream) {
  const float* prob  = (const float*)d_in[0];  // [B,H,W]
  const float* gtmap = (const float*)d_in[1];  // [B,H,W]
  const float* gt    = (const float*)d_in[2];  // [B,M,2]
  const float* osz   = (const float*)d_in[3];  // [B,2]
  float* out = (float*)d_out;

  unsigned* colmin  = (unsigned*)d_ws;                             // 1024 uints (4 KB)
  float* partials   = (float*)((char*)d_ws + 4096);                // NBLK*4 floats (16 KB)
  unsigned* counter = (unsigned*)((char*)d_ws + 4096 + NBLK * 16); // 1 uint

  whd_fused<<<NBLK, TPB, 0, stream>>>(prob, gtmap, gt, osz, colmin, partials,
                                      counter, out);
}